// Round 1
// baseline (1199.851 us; speedup 1.0000x reference)
//
#include <hip/hip_runtime.h>

#define NTHREADS 256

constexpr int CB = 4, CL = 2048, CH = 16, CE = 64;
constexpr int ROWSTRIDE = CH * CE;  // 1024 floats between consecutive seq positions

// LDS: K/V staging tiles (padded to 68 floats/row) reused as the merge buffer.
union SMem {
  float stage[2][64][68];  // [K|V][row][col]
  float macc[128][68];     // half-1 accumulators for the merge
};

__global__ __launch_bounds__(NTHREADS, 2)
void attn_fwd(const float* __restrict__ Q, const float* __restrict__ K,
              const float* __restrict__ V, float* __restrict__ O) {
  __shared__ SMem sm;
  __shared__ float sml[128][2];  // half-1 (m, l)

  const int tid  = threadIdx.x;
  const int lr   = tid & 127;   // local q row
  const int half = tid >> 7;    // key-split half: 0 or 1

  const int bid   = blockIdx.x;
  const int bh    = bid & 63;     // heads fastest -> heavy blocks spread over CUs
  const int qslot = bid >> 6;     // 0..15
  const int qbi   = 15 - qslot;   // heavy (long-row) blocks dispatched first
  const int b = bh >> 4, h = bh & 15;
  const int qb = qbi * 128;
  const int r  = qb + lr;         // this thread's query row

  // Q row -> registers (16 x float4 = 64 floats)
  const float* qptr = Q + ((size_t)(b * CL + r) * CH + h) * CE;
  float4 q4[16];
#pragma unroll
  for (int i = 0; i < 16; ++i) q4[i] = ((const float4*)qptr)[i];

  float4 a4[16];
#pragma unroll
  for (int i = 0; i < 16; ++i) a4[i] = make_float4(0.f, 0.f, 0.f, 0.f);
  float mrun = -1e30f, lrun = 0.f;

  const float* Kbase = K + ((size_t)b * CL * CH + h) * CE;
  const float* Vbase = V + ((size_t)b * CL * CH + h) * CE;

  const int   npairs = 2 * qbi + 2;  // 64-row tiles needed to cover rows qb..qb+127
  const float scale  = 0.125f;       // 1/sqrt(64)

  for (int p = 0; p < npairs; ++p) {
    const int kbase = p * 64;
    __syncthreads();  // previous tile's compute done before overwrite
    // Stage 64 rows of K and V: 1024 float4 per array, 4 per thread, coalesced
#pragma unroll
    for (int f = 0; f < 4; ++f) {
      const int idx = f * NTHREADS + tid;
      const int row = idx >> 4, c4 = idx & 15;
      const float4 t0 = *(const float4*)(Kbase + (size_t)(kbase + row) * ROWSTRIDE + c4 * 4);
      *(float4*)&sm.stage[0][row][c4 * 4] = t0;
      const float4 t1 = *(const float4*)(Vbase + (size_t)(kbase + row) * ROWSTRIDE + c4 * 4);
      *(float4*)&sm.stage[1][row][c4 * 4] = t1;
    }
    __syncthreads();

    const int myks = kbase + half * 32;  // this half's first key
    if (r < myks) continue;              // whole half-tile masked for this row

    for (int c = 0; c < 2; ++c) {        // 16-key chunks
      const int ck = myks + c * 16;      // first key of chunk (global index)
      if (r < ck) break;                 // rest of tile fully masked
      const int lrow0 = half * 32 + c * 16;

      // --- scores: s[jj] = scale * <q, K[ck+jj]>, causal-masked ---
      float s[16];
#pragma unroll
      for (int jj = 0; jj < 16; ++jj) {
        const float* krow = &sm.stage[0][lrow0 + jj][0];  // broadcast reads
        float sx = 0.f, sy = 0.f, sz = 0.f, sw = 0.f;
#pragma unroll
        for (int e4 = 0; e4 < 16; ++e4) {
          const float4 k4 = *(const float4*)(krow + e4 * 4);
          sx += q4[e4].x * k4.x;
          sy += q4[e4].y * k4.y;
          sz += q4[e4].z * k4.z;
          sw += q4[e4].w * k4.w;
        }
        const float dot = (sx + sy) + (sz + sw);
        s[jj] = (ck + jj <= r) ? dot * scale : -1e30f;
      }

      // --- online softmax update ---
      float cmax = -1e30f;
#pragma unroll
      for (int jj = 0; jj < 16; ++jj) cmax = fmaxf(cmax, s[jj]);
      const float mnew = fmaxf(mrun, cmax);
      const float corr = __expf(mrun - mnew);  // ==1 if unchanged; 0 if first real chunk
      mrun = mnew;
      lrun *= corr;
#pragma unroll
      for (int i = 0; i < 16; ++i) {
        a4[i].x *= corr; a4[i].y *= corr; a4[i].z *= corr; a4[i].w *= corr;
      }

      // --- P·V accumulate ---
#pragma unroll
      for (int jj = 0; jj < 16; ++jj) {
        const float pv = __expf(s[jj] - mrun);
        lrun += pv;
        const float* vrow = &sm.stage[1][lrow0 + jj][0];  // broadcast reads
#pragma unroll
        for (int d4 = 0; d4 < 16; ++d4) {
          const float4 v4 = *(const float4*)(vrow + d4 * 4);
          a4[d4].x += pv * v4.x;
          a4[d4].y += pv * v4.y;
          a4[d4].z += pv * v4.z;
          a4[d4].w += pv * v4.w;
        }
      }
    }
  }

  // --- merge the two key-split halves of each row ---
  __syncthreads();  // all staging-buffer reads done; safe to reuse as macc
  if (half == 1) {
#pragma unroll
    for (int d4 = 0; d4 < 16; ++d4)
      *(float4*)&sm.macc[lr][d4 * 4] = a4[d4];
    sml[lr][0] = mrun;
    sml[lr][1] = lrun;
  }
  __syncthreads();
  if (half == 0) {
    const float m1 = sml[lr][0], l1 = sml[lr][1];
    const float mstar = fmaxf(mrun, m1);
    const float f0 = __expf(mrun - mstar);
    const float f1 = __expf(m1 - mstar);    // ==0 if half1 saw no valid keys
    const float inv = 1.0f / (lrun * f0 + l1 * f1);
    float* optr = O + ((size_t)(b * CL + r) * CH + h) * CE;
#pragma unroll
    for (int d4 = 0; d4 < 16; ++d4) {
      const float4 o1 = *(const float4*)&sm.macc[lr][d4 * 4];
      float4 res;
      res.x = (a4[d4].x * f0 + o1.x * f1) * inv;
      res.y = (a4[d4].y * f0 + o1.y * f1) * inv;
      res.z = (a4[d4].z * f0 + o1.z * f1) * inv;
      res.w = (a4[d4].w * f0 + o1.w * f1) * inv;
      ((float4*)optr)[d4] = res;
    }
  }
}

extern "C" void kernel_launch(void* const* d_in, const int* in_sizes, int n_in,
                              void* d_out, int out_size, void* d_ws, size_t ws_size,
                              hipStream_t stream) {
  const float* Q = (const float*)d_in[0];
  const float* K = (const float*)d_in[1];
  const float* V = (const float*)d_in[2];
  float* O = (float*)d_out;
  // grid: 16 q-blocks (heavy-first) x 64 (b,h) pairs
  attn_fwd<<<dim3(16 * 64), dim3(NTHREADS), 0, stream>>>(Q, K, V, O);
}

// Round 2
// 279.702 us; speedup vs baseline: 4.2897x; 4.2897x over previous
//
#include <hip/hip_runtime.h>

typedef _Float16 half8  __attribute__((ext_vector_type(8)));
typedef _Float16 half4v __attribute__((ext_vector_type(4)));
typedef _Float16 half2v __attribute__((ext_vector_type(2)));
typedef float    f32x4  __attribute__((ext_vector_type(4)));

constexpr int CL = 2048, CH = 16, CE = 64;
constexpr int RS = CH * CE;  // 1024 floats between consecutive seq positions

__global__ __launch_bounds__(256, 4)
void attn_mfma(const float* __restrict__ Q, const float* __restrict__ K,
               const float* __restrict__ V, float* __restrict__ O) {
  // K tile row-major [key][e], XOR-swizzled; V tile transposed [d][key], XOR-swizzled.
  __shared__ _Float16 Ks[64 * 64];
  __shared__ _Float16 Vt[64 * 64];
  __shared__ _Float16 Pl[4][16 * 64];  // per-wave P strip (no cross-wave sync needed)

  const int tid = threadIdx.x;
  const int w = tid >> 6;        // wave 0..3
  const int l = tid & 63;        // lane
  const int lg = l >> 4;         // lane group 0..3
  const int lc = l & 15;         // lane col 0..15

  const int bid = blockIdx.x;
  const int bh = bid & 63;       // heads fastest
  const int qt = 31 - (bid >> 6);  // heavy (many-key-tile) blocks first
  const int b = bh >> 4, h = bh & 15;

  const int qg0 = qt * 64 + w * 16;  // wave's first global q row

  // ---- Q A-frags: lane holds row (l&15), k-cols (l>>4)*8..+7 per 32-wide e-chunk ----
  const float* qrow = Q + ((size_t)(b * CL + qg0 + lc) * CH + h) * CE;
  half8 qf[2];
#pragma unroll
  for (int e = 0; e < 2; ++e) {
    const float4 x0 = *(const float4*)(qrow + e * 32 + lg * 8);
    const float4 x1 = *(const float4*)(qrow + e * 32 + lg * 8 + 4);
    half8 t;
    t[0] = (_Float16)(x0.x * 0.125f); t[1] = (_Float16)(x0.y * 0.125f);
    t[2] = (_Float16)(x0.z * 0.125f); t[3] = (_Float16)(x0.w * 0.125f);
    t[4] = (_Float16)(x1.x * 0.125f); t[5] = (_Float16)(x1.y * 0.125f);
    t[6] = (_Float16)(x1.z * 0.125f); t[7] = (_Float16)(x1.w * 0.125f);
    qf[e] = t;
  }

  f32x4 acc[4];
#pragma unroll
  for (int i = 0; i < 4; ++i) acc[i] = (f32x4){0.f, 0.f, 0.f, 0.f};
  float m_[4], l_[4];
#pragma unroll
  for (int r = 0; r < 4; ++r) { m_[r] = -1e30f; l_[r] = 0.f; }

  const float* Kb = K + ((size_t)b * CL * CH + h) * CE;
  const float* Vb = V + ((size_t)b * CL * CH + h) * CE;
  _Float16* Plw = Pl[w];

  for (int kt = 0; kt <= qt; ++kt) {
    const int kb = kt * 64;
    __syncthreads();  // previous tile's reads done before overwrite

    // ---- stage K: 64x64 fp32 -> fp16, row-major + XOR swizzle ----
#pragma unroll
    for (int i = 0; i < 4; ++i) {
      const int idx = i * 256 + tid;
      const int row = idx >> 4, c4 = idx & 15;
      const float4 v = *(const float4*)(Kb + (size_t)(kb + row) * RS + c4 * 4);
      half4v hv;
      hv[0] = (_Float16)v.x; hv[1] = (_Float16)v.y;
      hv[2] = (_Float16)v.z; hv[3] = (_Float16)v.w;
      *(half4v*)&Ks[row * 64 + ((c4 * 4) ^ ((row & 7) << 3))] = hv;
    }
    // ---- stage V transposed: Vt[d][k] fp16 + XOR swizzle ----
#pragma unroll
    for (int i = 0; i < 2; ++i) {
      const int task = i * 256 + tid;
      const int d4 = task & 15, kp = task >> 4;  // kp 0..31 (key pair)
      const float4 v0 = *(const float4*)(Vb + (size_t)(kb + 2 * kp) * RS + d4 * 4);
      const float4 v1 = *(const float4*)(Vb + (size_t)(kb + 2 * kp + 1) * RS + d4 * 4);
      const float a0[4] = {v0.x, v0.y, v0.z, v0.w};
      const float a1[4] = {v1.x, v1.y, v1.z, v1.w};
#pragma unroll
      for (int j = 0; j < 4; ++j) {
        const int d = d4 * 4 + j;
        half2v hv;
        hv[0] = (_Float16)a0[j];
        hv[1] = (_Float16)a1[j];
        *(half2v*)&Vt[d * 64 + ((2 * kp) ^ ((d & 7) << 3))] = hv;
      }
    }
    __syncthreads();

    // ---- scores: S[16q][64k] per wave, 8 MFMAs ----
    f32x4 s[4];
#pragma unroll
    for (int kf = 0; kf < 4; ++kf) {
      const int row = kf * 16 + lc;  // key row in LDS
      const half8 b0 = *(const half8*)&Ks[row * 64 + ((lg * 8) ^ ((row & 7) << 3))];
      const half8 b1 = *(const half8*)&Ks[row * 64 + ((32 + lg * 8) ^ ((row & 7) << 3))];
      f32x4 z = {0.f, 0.f, 0.f, 0.f};
      z = __builtin_amdgcn_mfma_f32_16x16x32_f16(qf[0], b0, z, 0, 0, 0);
      z = __builtin_amdgcn_mfma_f32_16x16x32_f16(qf[1], b1, z, 0, 0, 0);
      s[kf] = z;
    }

    // ---- causal mask (diagonal tile only) ----
    if (kt == qt) {
#pragma unroll
      for (int kf = 0; kf < 4; ++kf) {
        const int kg = kb + kf * 16 + lc;
#pragma unroll
        for (int r = 0; r < 4; ++r) {
          const int qg = qg0 + lg * 4 + r;
          if (kg > qg) s[kf][r] = -1e30f;
        }
      }
    }

    // ---- online softmax (row = (lg)*4+r; reduce across the 16 col-lanes) ----
    float p32[4][4];
#pragma unroll
    for (int r = 0; r < 4; ++r) {
      float mt = fmaxf(fmaxf(s[0][r], s[1][r]), fmaxf(s[2][r], s[3][r]));
      mt = fmaxf(mt, __shfl_xor(mt, 1));
      mt = fmaxf(mt, __shfl_xor(mt, 2));
      mt = fmaxf(mt, __shfl_xor(mt, 4));
      mt = fmaxf(mt, __shfl_xor(mt, 8));
      const float mn = fmaxf(m_[r], mt);
      const float corr = __expf(m_[r] - mn);
      m_[r] = mn;
      float rs = 0.f;
#pragma unroll
      for (int kf = 0; kf < 4; ++kf) {
        const _Float16 ph = (_Float16)__expf(s[kf][r] - mn);
        const float pv = (float)ph;  // use rounded p for l too (common-mode cancel)
        p32[kf][r] = pv;
        rs += pv;
      }
      rs += __shfl_xor(rs, 1);
      rs += __shfl_xor(rs, 2);
      rs += __shfl_xor(rs, 4);
      rs += __shfl_xor(rs, 8);
      l_[r] = l_[r] * corr + rs;
#pragma unroll
      for (int df = 0; df < 4; ++df) acc[df][r] *= corr;
    }

    // ---- P -> per-wave LDS strip (A-frag layout source) ----
#pragma unroll
    for (int kf = 0; kf < 4; ++kf)
#pragma unroll
      for (int r = 0; r < 4; ++r) {
        const int q = lg * 4 + r;
        Plw[q * 64 + ((kf * 16 + lc) ^ ((q & 7) << 3))] = (_Float16)p32[kf][r];
      }

    // ---- PV: O[16q][64d] += P[16q][64k] * V[64k][64d], 8 MFMAs ----
#pragma unroll
    for (int c = 0; c < 2; ++c) {
      const half8 pa = *(const half8*)&Plw[lc * 64 + ((c * 32 + lg * 8) ^ ((lc & 7) << 3))];
#pragma unroll
      for (int df = 0; df < 4; ++df) {
        const int row = df * 16 + lc;  // d row in Vt
        const half8 vb = *(const half8*)&Vt[row * 64 + ((c * 32 + lg * 8) ^ ((row & 7) << 3))];
        acc[df] = __builtin_amdgcn_mfma_f32_16x16x32_f16(pa, vb, acc[df], 0, 0, 0);
      }
    }
  }

  // ---- epilogue: normalize and store fp32 ----
  float* Ob = O + ((size_t)(b * CL) * CH + h) * CE;
#pragma unroll
  for (int r = 0; r < 4; ++r) {
    const float inv = 1.0f / l_[r];
    const int qg = qg0 + lg * 4 + r;
    float* orow = Ob + (size_t)qg * RS;
#pragma unroll
    for (int df = 0; df < 4; ++df) orow[df * 16 + lc] = acc[df][r] * inv;
  }
}

extern "C" void kernel_launch(void* const* d_in, const int* in_sizes, int n_in,
                              void* d_out, int out_size, void* d_ws, size_t ws_size,
                              hipStream_t stream) {
  const float* Q = (const float*)d_in[0];
  const float* K = (const float*)d_in[1];
  const float* V = (const float*)d_in[2];
  float* O = (float*)d_out;
  // grid: 32 q-tiles (heavy-first) x 64 (b,h)
  attn_mfma<<<dim3(32 * 64), dim3(256), 0, stream>>>(Q, K, V, O);
}

// Round 5
// 232.804 us; speedup vs baseline: 5.1539x; 1.2015x over previous
//
#include <hip/hip_runtime.h>

typedef _Float16 half8  __attribute__((ext_vector_type(8)));
typedef _Float16 half4v __attribute__((ext_vector_type(4)));
typedef __fp16   pk2    __attribute__((ext_vector_type(2)));  // cvt_pkrtz result type
typedef float    f32x16 __attribute__((ext_vector_type(16)));

constexpr int CL = 2048, CH = 16, CE = 64;
constexpr int RS = CH * CE;  // 1024 floats between consecutive seq positions

union H8 { half8 v; pk2 h[4]; unsigned u[4]; };
union H4 { half4v v; pk2 h[2]; };
union H2 { pk2 h; unsigned u; };

// XOR swizzle on the inner (k/e) index, in units of 8 halves (16B).
// Injective over consecutive-8 rows (frag reads) AND stride-4 rows (V stage writes).
__device__ __forceinline__ int swz(int r) { return ((r ^ (r >> 3)) & 7) << 3; }

__global__ __launch_bounds__(256, 3)
void attn32(const float* __restrict__ Q, const float* __restrict__ K,
            const float* __restrict__ V, float* __restrict__ O) {
  // element (row, e) of K tile lives at KS[row*64 + (e ^ swz(row))]
  // element (k, d) of V tile lives at VT[d*64 + (k ^ swz(d))]   (transposed)
  __shared__ _Float16 KS[2][64 * 64];
  __shared__ _Float16 VT[2][64 * 64];

  const int tid = threadIdx.x;
  const int w  = tid >> 6, l = tid & 63;
  const int hi = l >> 5,  ql = l & 31;

  const int bid = blockIdx.x;
  const int bh  = bid & 63;          // heads fastest
  const int qt  = 15 - (bid >> 6);   // heavy blocks first
  const int b = bh >> 4, h = bh & 15;
  const int qg0 = qt * 128 + w * 32; // wave's first q row
  const int qg  = qg0 + ql;          // lane's q row

  // ---- Q^T B-frags (swapped QK^T): lane holds col q=ql, e-rows hi*8..+7 per 16-e chunk ----
  const float* qptr = Q + ((size_t)(b * CL + qg) * CH + h) * CE;
  const float qs = 0.125f * 1.44269504089f;  // softmax scale * log2(e)
  half8 qf[4];
#pragma unroll
  for (int c = 0; c < 4; ++c) {
    const float4 x0 = *(const float4*)(qptr + c * 16 + hi * 8);
    const float4 x1 = *(const float4*)(qptr + c * 16 + hi * 8 + 4);
    H8 t;
    t.h[0] = __builtin_amdgcn_cvt_pkrtz(x0.x * qs, x0.y * qs);
    t.h[1] = __builtin_amdgcn_cvt_pkrtz(x0.z * qs, x0.w * qs);
    t.h[2] = __builtin_amdgcn_cvt_pkrtz(x1.x * qs, x1.y * qs);
    t.h[3] = __builtin_amdgcn_cvt_pkrtz(x1.z * qs, x1.w * qs);
    qf[c] = t.v;
  }

  f32x16 acc0, acc1;  // O^T accumulators: col q=ql (lane-local), d-rows per reg
#pragma unroll
  for (int i = 0; i < 16; ++i) { acc0[i] = 0.f; acc1[i] = 0.f; }
  float m_ = -1e30f, l_ = 0.f;

  const float* Kb = K + ((size_t)b * CL * CH + h) * CE;
  const float* Vb = V + ((size_t)b * CL * CH + h) * CE;

  const int r0 = tid >> 4;  // staging: this thread's row-within-16
  const int c4 = tid & 15;  // staging: this thread's 16B column

  const int ktmax  = 2 * qt + 1;         // block's last 64-key tile
  const int ktlast = 2 * qt + (w >> 1);  // wave's last (diagonal) tile

  auto stage_write = [&](int buf, int i, const float4& kx, const float4& vx) {
    const int row = i * 16 + r0;         // key index within tile
    H4 t;
    t.h[0] = __builtin_amdgcn_cvt_pkrtz(kx.x, kx.y);
    t.h[1] = __builtin_amdgcn_cvt_pkrtz(kx.z, kx.w);
    *(half4v*)&KS[buf][row * 64 + ((c4 * 4) ^ swz(row))] = t.v;
    VT[buf][(c4 * 4 + 0) * 64 + (row ^ swz(c4 * 4 + 0))] = (_Float16)vx.x;
    VT[buf][(c4 * 4 + 1) * 64 + (row ^ swz(c4 * 4 + 1))] = (_Float16)vx.y;
    VT[buf][(c4 * 4 + 2) * 64 + (row ^ swz(c4 * 4 + 2))] = (_Float16)vx.z;
    VT[buf][(c4 * 4 + 3) * 64 + (row ^ swz(c4 * 4 + 3))] = (_Float16)vx.w;
  };

  // ---- prologue: stage tile 0 into buffer 0 ----
#pragma unroll
  for (int i = 0; i < 4; ++i) {
    const int row = i * 16 + r0;
    const float4 kx = *(const float4*)(Kb + (size_t)row * RS + c4 * 4);
    const float4 vx = *(const float4*)(Vb + (size_t)row * RS + c4 * 4);
    stage_write(0, i, kx, vx);
  }

  for (int kt = 0; kt <= ktmax; ++kt) {
    const int cur = kt & 1, nxt = cur ^ 1;
    __syncthreads();  // staged writes to cur visible; prev reads of nxt done

    // ---- issue next-tile global loads early (latency hides under compute) ----
    float4 kst[4], vst[4];
    const bool doStage = (kt < ktmax);
    if (doStage) {
      const int kb1 = (kt + 1) * 64;
#pragma unroll
      for (int i = 0; i < 4; ++i) {
        const int row = kb1 + i * 16 + r0;
        kst[i] = *(const float4*)(Kb + (size_t)row * RS + c4 * 4);
        vst[i] = *(const float4*)(Vb + (size_t)row * RS + c4 * 4);
      }
    }

    if (kt <= ktlast) {
      const int kb = kt * 64;
      const bool do1 = (qg0 + 31) >= (kb + 32);  // ktile1 has any valid keys (wave-uniform)

      // ---- swapped QK^T: S^T[k][q] = K_tile · Q^T ----
      f32x16 st0, st1;
#pragma unroll
      for (int i = 0; i < 16; ++i) { st0[i] = 0.f; st1[i] = 0.f; }
#pragma unroll
      for (int c = 0; c < 4; ++c) {
        const half8 ka = *(const half8*)&KS[cur][ql * 64 + ((c * 16 + hi * 8) ^ swz(ql))];
        st0 = __builtin_amdgcn_mfma_f32_32x32x16_f16(ka, qf[c], st0, 0, 0, 0);
      }
      if (do1) {
#pragma unroll
        for (int c = 0; c < 4; ++c) {
          const int row = 32 + ql;
          const half8 ka = *(const half8*)&KS[cur][row * 64 + ((c * 16 + hi * 8) ^ swz(row))];
          st1 = __builtin_amdgcn_mfma_f32_32x32x16_f16(ka, qf[c], st1, 0, 0, 0);
        }
      }

      // ---- causal mask (diagonal tile only); reg r -> k row (r&3)+8*(r>>2)+4*hi ----
      if (kt == ktlast) {
#pragma unroll
        for (int r = 0; r < 16; ++r) {
          const int ko = (r & 3) + 8 * (r >> 2) + 4 * hi;
          if (kb + ko > qg) st0[r] = -1e30f;
          if (kb + 32 + ko > qg) st1[r] = -1e30f;
        }
      }

      // ---- in-lane online softmax (lane owns row q=ql; other 32 keys in lane^32) ----
      float mt;
      {
        float a = fmaxf(fmaxf(fmaxf(st0[0], st0[1]), fmaxf(st0[2], st0[3])),
                        fmaxf(fmaxf(st0[4], st0[5]), fmaxf(st0[6], st0[7])));
        float bm = fmaxf(fmaxf(fmaxf(st0[8], st0[9]), fmaxf(st0[10], st0[11])),
                         fmaxf(fmaxf(st0[12], st0[13]), fmaxf(st0[14], st0[15])));
        mt = fmaxf(a, bm);
        if (do1) {
          float c2 = fmaxf(fmaxf(fmaxf(st1[0], st1[1]), fmaxf(st1[2], st1[3])),
                           fmaxf(fmaxf(st1[4], st1[5]), fmaxf(st1[6], st1[7])));
          float d2 = fmaxf(fmaxf(fmaxf(st1[8], st1[9]), fmaxf(st1[10], st1[11])),
                           fmaxf(fmaxf(st1[12], st1[13]), fmaxf(st1[14], st1[15])));
          mt = fmaxf(mt, fmaxf(c2, d2));
        }
      }
      mt = fmaxf(mt, __shfl_xor(mt, 32));
      const float mn = fmaxf(m_, mt);
      const float corr = exp2f(m_ - mn);
      m_ = mn;

      float rs = 0.f;
#pragma unroll
      for (int r = 0; r < 16; ++r) { st0[r] = exp2f(st0[r] - mn); rs += st0[r]; }
      if (do1) {
#pragma unroll
        for (int r = 0; r < 16; ++r) { st1[r] = exp2f(st1[r] - mn); rs += st1[r]; }
      }
      rs += __shfl_xor(rs, 32);
      l_ = l_ * corr + rs;
#pragma unroll
      for (int r = 0; r < 16; ++r) { acc0[r] *= corr; acc1[r] *= corr; }

      // ---- pack P to f16 words (consecutive-k pairs) ----
      unsigned W0[8], W1[8];
#pragma unroll
      for (int m = 0; m < 8; ++m) {
        H2 u; u.h = __builtin_amdgcn_cvt_pkrtz(st0[2 * m], st0[2 * m + 1]);
        W0[m] = u.u;
      }
      if (do1) {
#pragma unroll
        for (int m = 0; m < 8; ++m) {
          H2 u; u.h = __builtin_amdgcn_cvt_pkrtz(st1[2 * m], st1[2 * m + 1]);
          W1[m] = u.u;
        }
      }

      // ---- PV (O^T = V^T · P^T): B-frag of P via shfl_xor(32) redistribution ----
#pragma unroll
      for (int c2 = 0; c2 < 2; ++c2) {
        const unsigned s0 = (unsigned)__shfl_xor((int)W0[4 * c2 + 0], 32);
        const unsigned s1 = (unsigned)__shfl_xor((int)W0[4 * c2 + 1], 32);
        const unsigned s2 = (unsigned)__shfl_xor((int)W0[4 * c2 + 2], 32);
        const unsigned s3 = (unsigned)__shfl_xor((int)W0[4 * c2 + 3], 32);
        H8 f;
        f.u[0] = hi ? s2 : W0[4 * c2 + 0];
        f.u[1] = hi ? s3 : W0[4 * c2 + 1];
        f.u[2] = hi ? W0[4 * c2 + 2] : s0;
        f.u[3] = hi ? W0[4 * c2 + 3] : s1;
        const int kx = c2 * 16 + hi * 8;
        const int d0 = ql, d1 = 32 + ql;
        const half8 va0 = *(const half8*)&VT[cur][d0 * 64 + (kx ^ swz(d0))];
        const half8 va1 = *(const half8*)&VT[cur][d1 * 64 + (kx ^ swz(d1))];
        acc0 = __builtin_amdgcn_mfma_f32_32x32x16_f16(va0, f.v, acc0, 0, 0, 0);
        acc1 = __builtin_amdgcn_mfma_f32_32x32x16_f16(va1, f.v, acc1, 0, 0, 0);
      }
      if (do1) {
#pragma unroll
        for (int c2 = 0; c2 < 2; ++c2) {
          const unsigned s0 = (unsigned)__shfl_xor((int)W1[4 * c2 + 0], 32);
          const unsigned s1 = (unsigned)__shfl_xor((int)W1[4 * c2 + 1], 32);
          const unsigned s2 = (unsigned)__shfl_xor((int)W1[4 * c2 + 2], 32);
          const unsigned s3 = (unsigned)__shfl_xor((int)W1[4 * c2 + 3], 32);
          H8 f;
          f.u[0] = hi ? s2 : W1[4 * c2 + 0];
          f.u[1] = hi ? s3 : W1[4 * c2 + 1];
          f.u[2] = hi ? W1[4 * c2 + 2] : s0;
          f.u[3] = hi ? W1[4 * c2 + 3] : s1;
          const int kx = (2 + c2) * 16 + hi * 8;
          const int d0 = ql, d1 = 32 + ql;
          const half8 va0 = *(const half8*)&VT[cur][d0 * 64 + (kx ^ swz(d0))];
          const half8 va1 = *(const half8*)&VT[cur][d1 * 64 + (kx ^ swz(d1))];
          acc0 = __builtin_amdgcn_mfma_f32_32x32x16_f16(va0, f.v, acc0, 0, 0, 0);
          acc1 = __builtin_amdgcn_mfma_f32_32x32x16_f16(va1, f.v, acc1, 0, 0, 0);
        }
      }
    }

    // ---- write next tile to LDS (loads have had compute-time to land) ----
    if (doStage) {
#pragma unroll
      for (int i = 0; i < 4; ++i) stage_write(nxt, i, kst[i], vst[i]);
    }
  }

  // ---- epilogue: normalize (lane-local l_) and store O^T frags as float4 ----
  const float inv = 1.0f / l_;
  float* obase = O + ((size_t)(b * CL + qg) * CH + h) * CE;
#pragma unroll
  for (int rq = 0; rq < 4; ++rq) {
    float4 o;
    o.x = acc0[4 * rq + 0] * inv; o.y = acc0[4 * rq + 1] * inv;
    o.z = acc0[4 * rq + 2] * inv; o.w = acc0[4 * rq + 3] * inv;
    *(float4*)(obase + rq * 8 + hi * 4) = o;
  }
#pragma unroll
  for (int rq = 0; rq < 4; ++rq) {
    float4 o;
    o.x = acc1[4 * rq + 0] * inv; o.y = acc1[4 * rq + 1] * inv;
    o.z = acc1[4 * rq + 2] * inv; o.w = acc1[4 * rq + 3] * inv;
    *(float4*)(obase + 32 + rq * 8 + hi * 4) = o;
  }
}

extern "C" void kernel_launch(void* const* d_in, const int* in_sizes, int n_in,
                              void* d_out, int out_size, void* d_ws, size_t ws_size,
                              hipStream_t stream) {
  const float* Q = (const float*)d_in[0];
  const float* K = (const float*)d_in[1];
  const float* V = (const float*)d_in[2];
  float* O = (float*)d_out;
  (void)d_ws; (void)ws_size; (void)in_sizes; (void)n_in; (void)out_size;
  // grid: 16 q-tiles (heavy-first) x 64 (b,h)
  attn32<<<dim3(16 * 64), dim3(256), 0, stream>>>(Q, K, V, O);
}